// Round 1
// baseline (1647.131 us; speedup 1.0000x reference)
//
#include <hip/hip_runtime.h>
#include <hip/hip_bf16.h>

// TransformerSpatialAttention on MI355X (gfx950)
// B=8, C=192, H=W=256, WS=8 -> 8192 windows x 64 tokens x 192 ch, NH=8, HD=24.
//
// Algebraic reduction (carried over): out = sigmoid(xa . wbar + bbar);
// V never stored, projection GEMM never run.
//
// This revision: occupancy 1 -> 2 blocks/CU.
//  - LDS 136.7 KB -> 68 KB: P-staging (pcw, 40 KB) replaced by in-register
//    shuffle row-reduction; xn aliased under lq (+1 barrier); LN scratch
//    aliased under lk; logit folded into vwf.
//  - grid 256x32iter -> 512x16iter; __launch_bounds__(512,4) (VGPR<=128).

typedef __attribute__((ext_vector_type(4))) float floatx4;
typedef __attribute__((ext_vector_type(8))) short short8;

#define SCALE_Q 0.20412414523193154f   // 24^-0.5
#define LN_EPS 1e-5f

// ---- LDS layout (bytes) ----
#define RXN 200      // xn row stride in bf16 (192 + 8 pad)
#define RQK 264      // q/k row stride in bf16 (8 heads * 32 padded + 8)
#define OFF_Q  0         // lq [64][RQK] bf16 ; xn [64][RXN] aliases (LN phase only)
#define OFF_K  33792     // lk [64][RQK] bf16 ; LN scratch (4 KB) aliases (LN phase only)
#define OFF_VW 67584     // 8 heads * 64 f32 : vw accum (QKV phase) -> per-head logits (attn phase)
#define LDS_BYTES 69632  // 68 KB -> 2 blocks/CU (139,264 <= 163,840)

__device__ __forceinline__ floatx4 mfma16(short8 a, short8 b, floatx4 c) {
  return __builtin_amdgcn_mfma_f32_16x16x32_bf16(a, b, c, 0, 0, 0);
}

// ---------------------------------------------------------------------------
// prep: pack w_qkv^T into per-fragment lane order (bf16) + wbar/bbar
// wfrag layout: [ntile j (36)][kstep s (6)][lane (64)][8 bf16]
//   element = w_qkv[32s + (lane>>4)*8 + i][16j + (lane&15)]
// ---------------------------------------------------------------------------
__global__ void prep_kernel(const float* __restrict__ w_qkv,
                            const float* __restrict__ w_proj,
                            const float* __restrict__ b_proj,
                            __hip_bfloat16* __restrict__ wfrag,
                            float* __restrict__ wbar) {
  int tid = blockIdx.x * 256 + threadIdx.x;
  if (tid < 36 * 6 * 64) {
    int j = tid / 384, rem = tid % 384, ksr = rem / 64, l = rem % 64;
    int n  = 16 * j + (l & 15);
    int k0 = 32 * ksr + (l >> 4) * 8;
#pragma unroll
    for (int i = 0; i < 8; ++i)
      wfrag[(size_t)tid * 8 + i] = __float2bfloat16(w_qkv[(k0 + i) * 576 + n]);
  }
  if (tid < 192) {
    float s = 0.f;
    for (int c = 0; c < 192; ++c) s += w_proj[tid * 192 + c];
    wbar[tid] = s * (1.f / 192.f);
  } else if (tid == 192) {
    float s = 0.f;
    for (int c = 0; c < 192; ++c) s += b_proj[c];
    wbar[192] = s * (1.f / 192.f);
  }
}

// ---------------------------------------------------------------------------
// main fused kernel: 512 blocks (bb = blk%8 -> XCD-stable image,
// wh = (blk>>3)&31, hseg = blk>>8 column half), 16 windows each.
// 512 threads = 8 waves; wave w owns head w.
// Barriers per iter: A (LN scratch), B (xn), B2 (af loaded, alias handoff),
// C (q/k/vw), D (logits).
// ---------------------------------------------------------------------------
__global__ __launch_bounds__(512, 4) void swin_kernel(
    const float* __restrict__ x,
    const float* __restrict__ gamma,
    const float* __restrict__ beta,
    const float* __restrict__ b_qkv,
    const __hip_bfloat16* __restrict__ wfrag,
    const float* __restrict__ wbar,
    float* __restrict__ out) {
  __shared__ __align__(16) char smem[LDS_BYTES];
  __hip_bfloat16* xn = (__hip_bfloat16*)(smem + OFF_Q);   // alias of lq (LN phase)
  __hip_bfloat16* lq = (__hip_bfloat16*)(smem + OFF_Q);
  __hip_bfloat16* lk = (__hip_bfloat16*)(smem + OFF_K);
  float* vwf = (float*)(smem + OFF_VW);
  float2* scratch = (float2*)(smem + OFF_K);              // alias of lk (LN phase)

  const int tid = threadIdx.x;
  const int w   = tid >> 6;
  const int l   = tid & 63;
  const int l15 = l & 15;
  const int lg  = l >> 4;
  const floatx4 fzero = {0.f, 0.f, 0.f, 0.f};

  const int p    = blockIdx.x;
  const int bb   = p & 7;              // image (== XCD under blockIdx%8 round-robin)
  const int wh   = (p >> 3) & 31;      // window row
  const int hseg = p >> 8;             // column half: ww = hseg*16 + it
  const int tr = l >> 3, tc = l & 7;   // lane <-> token (r,c) in 8x8 window
  const int c0 = w * 24;               // this wave's channel slice
  const float* xb = x + (size_t)bb * 192 * 65536 + (size_t)(wh * 8 + tr) * 256
                      + hseg * 128 + tc;

  float xr[24];
#pragma unroll
  for (int i = 0; i < 24; ++i) xr[i] = xb[(size_t)(c0 + i) * 65536];

#pragma unroll 1
  for (int it = 0; it < 16; ++it) {
    // ---------------- LayerNorm (lane = token, regs hold 24 channels) -------
    float s1 = 0.f, s2 = 0.f;
#pragma unroll
    for (int i = 0; i < 24; ++i) { s1 += xr[i]; s2 += xr[i] * xr[i]; }
    scratch[w * 64 + l] = make_float2(s1, s2);
    __syncthreads();                                           // (A)
    float ts = 0.f, tq = 0.f;
#pragma unroll
    for (int g = 0; g < 8; ++g) { float2 v = scratch[g * 64 + l]; ts += v.x; tq += v.y; }
    vwf[tid] = 0.f;   // reset vw accum for this window (fenced by A before / B after)
    const float mu   = ts * (1.f / 192.f);
    const float rstd = rsqrtf(tq * (1.f / 192.f) - mu * mu + LN_EPS);
#pragma unroll
    for (int i = 0; i < 24; ++i) {
      float xv = (xr[i] - mu) * rstd * gamma[c0 + i] + beta[c0 + i];
      xn[l * RXN + c0 + i] = __float2bfloat16(xv);
    }
    __syncthreads();                                           // (B)

    // A fragments cached in regs (96 VGPRs) -- required: xn dies at B2
    short8 af[4][6];
#pragma unroll
    for (int mi = 0; mi < 4; ++mi)
#pragma unroll
      for (int ks = 0; ks < 6; ++ks)
        af[mi][ks] = *(const short8*)&xn[(16 * mi + l15) * RXN + 32 * ks + lg * 8];
    __syncthreads();                                           // (B2) xn dead; lq/lk writable

    // re-zero q/k head-pad columns (d=24..31) -- clobbered by the xn alias
    {
      const short8 zz = {0, 0, 0, 0, 0, 0, 0, 0};
#pragma unroll
      for (int i2 = tid; i2 < 1024; i2 += 512) {
        int sel = i2 & 1, r2 = i2 >> 1;                        // r2 = t*8 + head
        __hip_bfloat16* dst = (sel ? lk : lq) + (r2 >> 3) * RQK + (r2 & 7) * 32 + 24;
        *(short8*)dst = zz;                                    // 16B aligned (528t+64h+48)
      }
    }

    // ---------------- QKV GEMM: xn(64x192) @ w_qkv(192x576) -----------------
    for (int j = w; j < 36; j += 8) {          // n-tiles round-robin over waves
      floatx4 aa[4];
#pragma unroll
      for (int mi = 0; mi < 4; ++mi) aa[mi] = fzero;
      const short8* bp = (const short8*)wfrag + (size_t)(j * 384 + l);
#pragma unroll
      for (int ks = 0; ks < 6; ++ks) {
        short8 bf = bp[ks * 64];               // coalesced 1KB, L2-resident
#pragma unroll
        for (int mi = 0; mi < 4; ++mi) aa[mi] = mfma16(af[mi][ks], bf, aa[mi]);
      }
      const int n = 16 * j + l15;
      const float bias = b_qkv[n];
      if (j < 12) {                            // ---- Q (SCALE folded in) ----
        const int hh = n / 24, dd = n - hh * 24;
#pragma unroll
        for (int mi = 0; mi < 4; ++mi)
#pragma unroll
          for (int rg = 0; rg < 4; ++rg) {
            int t = 16 * mi + lg * 4 + rg;
            lq[t * RQK + hh * 32 + dd] = __float2bfloat16((aa[mi][rg] + bias) * SCALE_Q);
          }
      } else if (j < 24) {                     // ---- K ----
        const int cc = n - 192;
        const int hh = cc / 24, dd = cc - hh * 24;
#pragma unroll
        for (int mi = 0; mi < 4; ++mi)
#pragma unroll
          for (int rg = 0; rg < 4; ++rg) {
            int t = 16 * mi + lg * 4 + rg;
            lk[t * RQK + hh * 32 + dd] = __float2bfloat16(aa[mi][rg] + bias);
          }
      } else {                                 // ---- V: reduce straight to vw ----
        const int cc = n - 384;
        const int hh = cc / 24;                // head boundaries are 8-aligned (8|24)
        const float wbv = wbar[cc];
        float part[16];
#pragma unroll
        for (int mi = 0; mi < 4; ++mi)
#pragma unroll
          for (int rg = 0; rg < 4; ++rg)
            part[mi * 4 + rg] = (aa[mi][rg] + bias) * wbv;
#pragma unroll
        for (int v2 = 0; v2 < 16; ++v2) {      // head-pure 8-lane reduction
          float t0 = part[v2];
          t0 += __shfl_xor(t0, 1);
          t0 += __shfl_xor(t0, 2);
          t0 += __shfl_xor(t0, 4);
          part[v2] = t0;
        }
        if ((l15 & 7) == 0) {
#pragma unroll
          for (int mi = 0; mi < 4; ++mi)
#pragma unroll
            for (int rg = 0; rg < 4; ++rg) {
              int t = 16 * mi + lg * 4 + rg;
              atomicAdd(&vwf[hh * 64 + t], part[mi * 4 + rg]);
            }
        }
      }
    }

    // prefetch next window's x (after j-loop: frees VGPR peak; attention
    // phase provides ample latency cover before next-iteration use)
    if (it < 15) {
#pragma unroll
      for (int i = 0; i < 24; ++i)
        xr[i] = xb[(size_t)(c0 + i) * 65536 + (it + 1) * 8];
    }
    __syncthreads();                                           // (C)

    // ---------------- attention: wave w = head w -----------------------------
    {
      const int hh = w;
      short8 qf[4], kf[4];
#pragma unroll
      for (int i = 0; i < 4; ++i) {
        qf[i] = *(const short8*)&lq[(16 * i + l15) * RQK + hh * 32 + lg * 8];
        kf[i] = *(const short8*)&lk[(16 * i + l15) * RQK + hh * 32 + lg * 8];
      }
      float vwv[4];                            // this head's vw vector slice
#pragma unroll
      for (int j2 = 0; j2 < 4; ++j2) vwv[j2] = vwf[hh * 64 + 16 * j2 + l15];

      floatx4 sc[4][4];                        // S = q.k^T (scaled), then exp
#pragma unroll
      for (int i = 0; i < 4; ++i)
#pragma unroll
        for (int j2 = 0; j2 < 4; ++j2)
          sc[i][j2] = mfma16(qf[i], kf[j2], fzero);
#pragma unroll
      for (int i = 0; i < 4; ++i)
#pragma unroll
        for (int j2 = 0; j2 < 4; ++j2)
#pragma unroll
          for (int rg = 0; rg < 4; ++rg)
            sc[i][j2][rg] = exp2f(sc[i][j2][rg] * 1.44269504f);  // |s|<~40, fp32 safe

      // row-reduce in-register: D-layout row t = 16i + lg*4 + rg spans the 16
      // lanes of one lane-group (col = l15) x 4 j2 tiles.
      //   num[t] = sum_s P[t][s]*vw[s],  den[t] = sum_s P[t][s]
#pragma unroll
      for (int i = 0; i < 4; ++i) {
        float num[4] = {0.f, 0.f, 0.f, 0.f};
        float den[4] = {0.f, 0.f, 0.f, 0.f};
#pragma unroll
        for (int j2 = 0; j2 < 4; ++j2)
#pragma unroll
          for (int rg = 0; rg < 4; ++rg) {
            float pv = sc[i][j2][rg];
            den[rg] += pv;
            num[rg] = fmaf(pv, vwv[j2], num[rg]);
          }
#pragma unroll
        for (int m = 1; m < 16; m <<= 1)       // butterfly over l15 (in-group)
#pragma unroll
          for (int rg = 0; rg < 4; ++rg) {
            num[rg] += __shfl_xor(num[rg], m);
            den[rg] += __shfl_xor(den[rg], m);
          }
        // one unique lane per (i,rg) per lane-group stores the row's logit;
        // overwrites this wave's own (already-consumed) vw slice.
#pragma unroll
        for (int rg = 0; rg < 4; ++rg)
          if (l15 == i * 4 + rg)
            vwf[hh * 64 + 16 * i + lg * 4 + rg] = __fdividef(num[rg], den[rg]);
      }
    }
    __syncthreads();                                           // (D)

    // ---------------- epilogue: sum 8 per-head logits -----------------------
    if (tid < 64) {
      float vL = wbar[192];
#pragma unroll
      for (int h8 = 0; h8 < 8; ++h8) vL += vwf[h8 * 64 + tid];
      out[(size_t)bb * 65536 + (size_t)(wh * 8 + (tid >> 3)) * 256
          + hseg * 128 + it * 8 + (tid & 7)] = 1.f / (1.f + __expf(-vL));
    }
  }
}

// ---------------------------------------------------------------------------
extern "C" void kernel_launch(void* const* d_in, const int* in_sizes, int n_in,
                              void* d_out, int out_size, void* d_ws, size_t ws_size,
                              hipStream_t stream) {
  const float* x      = (const float*)d_in[0];
  const float* gamma  = (const float*)d_in[1];
  const float* beta   = (const float*)d_in[2];
  const float* w_qkv  = (const float*)d_in[3];
  const float* b_qkv  = (const float*)d_in[4];
  const float* w_proj = (const float*)d_in[5];
  const float* b_proj = (const float*)d_in[6];
  float* out = (float*)d_out;

  __hip_bfloat16* wfrag = (__hip_bfloat16*)d_ws;          // 221184 B
  float* wbar = (float*)((char*)d_ws + 221184);           // 193 f32 (wbar + bbar)

  prep_kernel<<<54, 256, 0, stream>>>(w_qkv, w_proj, b_proj, wfrag, wbar);
  swin_kernel<<<512, 512, 0, stream>>>(x, gamma, beta, b_qkv, wfrag, wbar, out);
}

// Round 2
// 1546.511 us; speedup vs baseline: 1.0651x; 1.0651x over previous
//
#include <hip/hip_runtime.h>
#include <hip/hip_bf16.h>

// TransformerSpatialAttention on MI355X (gfx950)
// B=8, C=192, H=W=256, WS=8 -> 8192 windows x 64 tokens x 192 ch, NH=8, HD=24.
//
// Algebraic reduction (carried over): out = sigmoid(xa . wbar + bbar);
// V never stored, projection GEMM never run.
//
// Round-2 fix: round 1 spilled (VGPR forced to 64 by launch_bounds(512,4) ->
// waves-per-eu range [4,8], allocator chased 8). Pin amdgpu_waves_per_eu(4,4)
// -> exact 128-VGPR budget, 2 blocks/CU. Plus: per-mi V reduction (smaller
// transient), x-prefetch moved after barrier D (no overlap with attention
// registers), xn stores packed as ds_write_b128 (bank-conflict-free).

typedef __attribute__((ext_vector_type(4))) float floatx4;
typedef __attribute__((ext_vector_type(8))) short short8;

#define SCALE_Q 0.20412414523193154f   // 24^-0.5
#define LN_EPS 1e-5f

// ---- LDS layout (bytes) ----
#define RXN 200      // xn row stride in bf16 (192 + 8 pad)
#define RQK 264      // q/k row stride in bf16 (8 heads * 32 padded + 8)
#define OFF_Q  0         // lq [64][RQK] bf16 ; xn [64][RXN] aliases (LN phase only)
#define OFF_K  33792     // lk [64][RQK] bf16 ; LN scratch (4 KB) aliases (LN phase only)
#define OFF_VW 67584     // 8 heads * 64 f32 : vw accum (QKV phase) -> per-head logits
#define LDS_BYTES 69632  // 68 KB -> 2 blocks/CU (139,264 <= 163,840)

__device__ __forceinline__ floatx4 mfma16(short8 a, short8 b, floatx4 c) {
  return __builtin_amdgcn_mfma_f32_16x16x32_bf16(a, b, c, 0, 0, 0);
}

// ---------------------------------------------------------------------------
// prep: pack w_qkv^T into per-fragment lane order (bf16) + wbar/bbar
// wfrag layout: [ntile j (36)][kstep s (6)][lane (64)][8 bf16]
//   element = w_qkv[32s + (lane>>4)*8 + i][16j + (lane&15)]
// ---------------------------------------------------------------------------
__global__ void prep_kernel(const float* __restrict__ w_qkv,
                            const float* __restrict__ w_proj,
                            const float* __restrict__ b_proj,
                            __hip_bfloat16* __restrict__ wfrag,
                            float* __restrict__ wbar) {
  int tid = blockIdx.x * 256 + threadIdx.x;
  if (tid < 36 * 6 * 64) {
    int j = tid / 384, rem = tid % 384, ksr = rem / 64, l = rem % 64;
    int n  = 16 * j + (l & 15);
    int k0 = 32 * ksr + (l >> 4) * 8;
#pragma unroll
    for (int i = 0; i < 8; ++i)
      wfrag[(size_t)tid * 8 + i] = __float2bfloat16(w_qkv[(k0 + i) * 576 + n]);
  }
  if (tid < 192) {
    float s = 0.f;
    for (int c = 0; c < 192; ++c) s += w_proj[tid * 192 + c];
    wbar[tid] = s * (1.f / 192.f);
  } else if (tid == 192) {
    float s = 0.f;
    for (int c = 0; c < 192; ++c) s += b_proj[c];
    wbar[192] = s * (1.f / 192.f);
  }
}

// ---------------------------------------------------------------------------
// main fused kernel: 512 blocks (bb = blk%8 -> XCD-stable image,
// wh = (blk>>3)&31, hseg = blk>>8 column half), 16 windows each.
// 512 threads = 8 waves; wave w owns head w.
// Barriers per iter: A (LN scratch), B (xn), B2 (af loaded, alias handoff),
// C (q/k/vw), D (logits).
// ---------------------------------------------------------------------------
__global__ void __launch_bounds__(512)
__attribute__((amdgpu_waves_per_eu(4, 4))) swin_kernel(
    const float* __restrict__ x,
    const float* __restrict__ gamma,
    const float* __restrict__ beta,
    const float* __restrict__ b_qkv,
    const __hip_bfloat16* __restrict__ wfrag,
    const float* __restrict__ wbar,
    float* __restrict__ out) {
  __shared__ __align__(16) char smem[LDS_BYTES];
  __hip_bfloat16* xn = (__hip_bfloat16*)(smem + OFF_Q);   // alias of lq (LN phase)
  __hip_bfloat16* lq = (__hip_bfloat16*)(smem + OFF_Q);
  __hip_bfloat16* lk = (__hip_bfloat16*)(smem + OFF_K);
  float* vwf = (float*)(smem + OFF_VW);
  float2* scratch = (float2*)(smem + OFF_K);              // alias of lk (LN phase)

  const int tid = threadIdx.x;
  const int w   = tid >> 6;
  const int l   = tid & 63;
  const int l15 = l & 15;
  const int lg  = l >> 4;
  const floatx4 fzero = {0.f, 0.f, 0.f, 0.f};

  const int p    = blockIdx.x;
  const int bb   = p & 7;              // image (== XCD under blockIdx%8 round-robin)
  const int wh   = (p >> 3) & 31;      // window row
  const int hseg = p >> 8;             // column half: ww = hseg*16 + it
  const int tr = l >> 3, tc = l & 7;   // lane <-> token (r,c) in 8x8 window
  const int c0 = w * 24;               // this wave's channel slice
  const float* xb = x + (size_t)bb * 192 * 65536 + (size_t)(wh * 8 + tr) * 256
                      + hseg * 128 + tc;

  float xr[24];
#pragma unroll
  for (int i = 0; i < 24; ++i) xr[i] = xb[(size_t)(c0 + i) * 65536];

#pragma unroll 1
  for (int it = 0; it < 16; ++it) {
    // ---------------- LayerNorm (lane = token, regs hold 24 channels) -------
    float s1 = 0.f, s2 = 0.f;
#pragma unroll
    for (int i = 0; i < 24; ++i) { s1 += xr[i]; s2 += xr[i] * xr[i]; }
    scratch[w * 64 + l] = make_float2(s1, s2);
    __syncthreads();                                           // (A)
    float ts = 0.f, tq = 0.f;
#pragma unroll
    for (int g = 0; g < 8; ++g) { float2 v = scratch[g * 64 + l]; ts += v.x; tq += v.y; }
    vwf[tid] = 0.f;   // reset vw accum for this window (fenced by A before / B after)
    const float mu   = ts * (1.f / 192.f);
    const float rstd = rsqrtf(tq * (1.f / 192.f) - mu * mu + LN_EPS);
    {
      short8 pk[3];
#pragma unroll
      for (int i = 0; i < 24; ++i) {
        float xv = (xr[i] - mu) * rstd * gamma[c0 + i] + beta[c0 + i];
        __hip_bfloat16 hb = __float2bfloat16(xv);
        short sv; __builtin_memcpy(&sv, &hb, 2);
        pk[i >> 3][i & 7] = sv;
      }
#pragma unroll
      for (int q2 = 0; q2 < 3; ++q2)          // b128 stores: conflict-free
        *(short8*)&xn[l * RXN + c0 + q2 * 8] = pk[q2];
    }
    __syncthreads();                                           // (B)

    // A fragments cached in regs (96 VGPRs) -- required: xn dies at B2
    short8 af[4][6];
#pragma unroll
    for (int mi = 0; mi < 4; ++mi)
#pragma unroll
      for (int ks = 0; ks < 6; ++ks)
        af[mi][ks] = *(const short8*)&xn[(16 * mi + l15) * RXN + 32 * ks + lg * 8];
    __syncthreads();                                           // (B2) xn dead; lq/lk writable

    // re-zero q/k head-pad columns (d=24..31) -- clobbered by the xn alias
    {
      const short8 zz = {0, 0, 0, 0, 0, 0, 0, 0};
#pragma unroll
      for (int i2 = tid; i2 < 1024; i2 += 512) {
        int sel = i2 & 1, r2 = i2 >> 1;                        // r2 = t*8 + head
        __hip_bfloat16* dst = (sel ? lk : lq) + (r2 >> 3) * RQK + (r2 & 7) * 32 + 24;
        *(short8*)dst = zz;                                    // 16B aligned (528t+64h+48)
      }
    }

    // ---------------- QKV GEMM: xn(64x192) @ w_qkv(192x576) -----------------
    for (int j = w; j < 36; j += 8) {          // n-tiles round-robin over waves
      floatx4 aa[4];
#pragma unroll
      for (int mi = 0; mi < 4; ++mi) aa[mi] = fzero;
      const short8* bp = (const short8*)wfrag + (size_t)(j * 384 + l);
#pragma unroll
      for (int ks = 0; ks < 6; ++ks) {
        short8 bf = bp[ks * 64];               // coalesced 1KB, L2-resident
#pragma unroll
        for (int mi = 0; mi < 4; ++mi) aa[mi] = mfma16(af[mi][ks], bf, aa[mi]);
      }
      const int n = 16 * j + l15;
      const float bias = b_qkv[n];
      if (j < 12) {                            // ---- Q (SCALE folded in) ----
        const int hh = n / 24, dd = n - hh * 24;
#pragma unroll
        for (int mi = 0; mi < 4; ++mi)
#pragma unroll
          for (int rg = 0; rg < 4; ++rg) {
            int t = 16 * mi + lg * 4 + rg;
            lq[t * RQK + hh * 32 + dd] = __float2bfloat16((aa[mi][rg] + bias) * SCALE_Q);
          }
      } else if (j < 24) {                     // ---- K ----
        const int cc = n - 192;
        const int hh = cc / 24, dd = cc - hh * 24;
#pragma unroll
        for (int mi = 0; mi < 4; ++mi)
#pragma unroll
          for (int rg = 0; rg < 4; ++rg) {
            int t = 16 * mi + lg * 4 + rg;
            lk[t * RQK + hh * 32 + dd] = __float2bfloat16(aa[mi][rg] + bias);
          }
      } else {                                 // ---- V: reduce straight to vw ----
        const int cc = n - 384;
        const int hh = cc / 24;                // head boundaries are 8-aligned (8|24)
        const float wbv = wbar[cc];
#pragma unroll
        for (int mi = 0; mi < 4; ++mi) {       // per-mi: small transient (part[4])
          float part[4];
#pragma unroll
          for (int rg = 0; rg < 4; ++rg)
            part[rg] = (aa[mi][rg] + bias) * wbv;
#pragma unroll
          for (int rg = 0; rg < 4; ++rg) {     // head-pure 8-lane reduction
            float t0 = part[rg];
            t0 += __shfl_xor(t0, 1);
            t0 += __shfl_xor(t0, 2);
            t0 += __shfl_xor(t0, 4);
            part[rg] = t0;
          }
          if ((l15 & 7) == 0)
#pragma unroll
            for (int rg = 0; rg < 4; ++rg) {
              int t = 16 * mi + lg * 4 + rg;
              atomicAdd(&vwf[hh * 64 + t], part[rg]);
            }
        }
      }
    }
    __syncthreads();                                           // (C)

    // ---------------- attention: wave w = head w -----------------------------
    {
      const int hh = w;
      short8 qf[4], kf[4];
#pragma unroll
      for (int i = 0; i < 4; ++i) {
        qf[i] = *(const short8*)&lq[(16 * i + l15) * RQK + hh * 32 + lg * 8];
        kf[i] = *(const short8*)&lk[(16 * i + l15) * RQK + hh * 32 + lg * 8];
      }
      float vwv[4];                            // this head's vw vector slice
#pragma unroll
      for (int j2 = 0; j2 < 4; ++j2) vwv[j2] = vwf[hh * 64 + 16 * j2 + l15];

      floatx4 sc[4][4];                        // S = q.k^T (scaled), then exp
#pragma unroll
      for (int i = 0; i < 4; ++i)
#pragma unroll
        for (int j2 = 0; j2 < 4; ++j2)
          sc[i][j2] = mfma16(qf[i], kf[j2], fzero);
#pragma unroll
      for (int i = 0; i < 4; ++i)
#pragma unroll
        for (int j2 = 0; j2 < 4; ++j2)
#pragma unroll
          for (int rg = 0; rg < 4; ++rg)
            sc[i][j2][rg] = exp2f(sc[i][j2][rg] * 1.44269504f);  // |s|<~40, fp32 safe

      // row-reduce in-register: D-layout row t = 16i + lg*4 + rg spans the 16
      // lanes of one lane-group (col = l15) x 4 j2 tiles.
      //   num[t] = sum_s P[t][s]*vw[s],  den[t] = sum_s P[t][s]
#pragma unroll
      for (int i = 0; i < 4; ++i) {
        float num[4] = {0.f, 0.f, 0.f, 0.f};
        float den[4] = {0.f, 0.f, 0.f, 0.f};
#pragma unroll
        for (int j2 = 0; j2 < 4; ++j2)
#pragma unroll
          for (int rg = 0; rg < 4; ++rg) {
            float pv = sc[i][j2][rg];
            den[rg] += pv;
            num[rg] = fmaf(pv, vwv[j2], num[rg]);
          }
#pragma unroll
        for (int m = 1; m < 16; m <<= 1)       // butterfly over l15 (in-group)
#pragma unroll
          for (int rg = 0; rg < 4; ++rg) {
            num[rg] += __shfl_xor(num[rg], m);
            den[rg] += __shfl_xor(den[rg], m);
          }
        // one unique lane per (i,rg) per lane-group stores the row's logit;
        // overwrites this wave's own (already-consumed) vw slice.
#pragma unroll
        for (int rg = 0; rg < 4; ++rg)
          if (l15 == i * 4 + rg)
            vwf[hh * 64 + 16 * i + lg * 4 + rg] = __fdividef(num[rg], den[rg]);
      }
    }
    __syncthreads();                                           // (D)

    // prefetch next window's x (live range overlaps only the epilogue; TLP
    // at 16 waves/CU covers the latency into next iteration's LN)
    if (it < 15) {
#pragma unroll
      for (int i = 0; i < 24; ++i)
        xr[i] = xb[(size_t)(c0 + i) * 65536 + (it + 1) * 8];
    }

    // ---------------- epilogue: sum 8 per-head logits -----------------------
    if (tid < 64) {
      float vL = wbar[192];
#pragma unroll
      for (int h8 = 0; h8 < 8; ++h8) vL += vwf[h8 * 64 + tid];
      out[(size_t)bb * 65536 + (size_t)(wh * 8 + (tid >> 3)) * 256
          + hseg * 128 + it * 8 + (tid & 7)] = 1.f / (1.f + __expf(-vL));
    }
  }
}

// ---------------------------------------------------------------------------
extern "C" void kernel_launch(void* const* d_in, const int* in_sizes, int n_in,
                              void* d_out, int out_size, void* d_ws, size_t ws_size,
                              hipStream_t stream) {
  const float* x      = (const float*)d_in[0];
  const float* gamma  = (const float*)d_in[1];
  const float* beta   = (const float*)d_in[2];
  const float* w_qkv  = (const float*)d_in[3];
  const float* b_qkv  = (const float*)d_in[4];
  const float* w_proj = (const float*)d_in[5];
  const float* b_proj = (const float*)d_in[6];
  float* out = (float*)d_out;

  __hip_bfloat16* wfrag = (__hip_bfloat16*)d_ws;          // 221184 B
  float* wbar = (float*)((char*)d_ws + 221184);           // 193 f32 (wbar + bbar)

  prep_kernel<<<54, 256, 0, stream>>>(w_qkv, w_proj, b_proj, wfrag, wbar);
  swin_kernel<<<512, 512, 0, stream>>>(x, gamma, beta, b_qkv, wfrag, wbar, out);
}

// Round 3
// 1284.854 us; speedup vs baseline: 1.2820x; 1.2036x over previous
//
#include <hip/hip_runtime.h>
#include <hip/hip_bf16.h>

// TransformerSpatialAttention on MI355X (gfx950)
// B=8, C=192, H=W=256, WS=8 -> 8192 windows x 64 tokens x 192 ch, NH=8, HD=24.
//
// Algebraic reduction (carried over): out = sigmoid(xa . wbar + bbar);
// V never stored, projection GEMM never run.
//
// Round-3: rounds 1/2 spilled because min-waves-per-EU=4 (launch_bounds arg or
// amdgpu_waves_per_eu(4,4)) makes the allocator target 8 waves/EU -> 64 VGPR
// -> ~96 regs of MFMA fragments spilled (WRITE_SIZE 0.65-1.05 GB). Empirically
// __launch_bounds__(512, 2) yields exactly 128 VGPR, no spill (round 0).
// Keep: 68 KB LDS (2 blocks/CU), in-register P row-reduction, aliased xn/LN
// scratch, b128 xn stores, per-mi V reduction, prefetch after barrier D.

typedef __attribute__((ext_vector_type(4))) float floatx4;
typedef __attribute__((ext_vector_type(8))) short short8;

#define SCALE_Q 0.20412414523193154f   // 24^-0.5
#define LN_EPS 1e-5f

// ---- LDS layout (bytes) ----
#define RXN 200      // xn row stride in bf16 (192 + 8 pad)
#define RQK 264      // q/k row stride in bf16 (8 heads * 32 padded + 8)
#define OFF_Q  0         // lq [64][RQK] bf16 ; xn [64][RXN] aliases (LN phase only)
#define OFF_K  33792     // lk [64][RQK] bf16 ; LN scratch (4 KB) aliases (LN phase only)
#define OFF_VW 67584     // 8 heads * 64 f32 : vw accum (QKV phase) -> per-head logits
#define LDS_BYTES 69632  // 68 KB -> 2 blocks/CU (139,264 <= 163,840)

__device__ __forceinline__ floatx4 mfma16(short8 a, short8 b, floatx4 c) {
  return __builtin_amdgcn_mfma_f32_16x16x32_bf16(a, b, c, 0, 0, 0);
}

// ---------------------------------------------------------------------------
// prep: pack w_qkv^T into per-fragment lane order (bf16) + wbar/bbar
// wfrag layout: [ntile j (36)][kstep s (6)][lane (64)][8 bf16]
//   element = w_qkv[32s + (lane>>4)*8 + i][16j + (lane&15)]
// ---------------------------------------------------------------------------
__global__ void prep_kernel(const float* __restrict__ w_qkv,
                            const float* __restrict__ w_proj,
                            const float* __restrict__ b_proj,
                            __hip_bfloat16* __restrict__ wfrag,
                            float* __restrict__ wbar) {
  int tid = blockIdx.x * 256 + threadIdx.x;
  if (tid < 36 * 6 * 64) {
    int j = tid / 384, rem = tid % 384, ksr = rem / 64, l = rem % 64;
    int n  = 16 * j + (l & 15);
    int k0 = 32 * ksr + (l >> 4) * 8;
#pragma unroll
    for (int i = 0; i < 8; ++i)
      wfrag[(size_t)tid * 8 + i] = __float2bfloat16(w_qkv[(k0 + i) * 576 + n]);
  }
  if (tid < 192) {
    float s = 0.f;
    for (int c = 0; c < 192; ++c) s += w_proj[tid * 192 + c];
    wbar[tid] = s * (1.f / 192.f);
  } else if (tid == 192) {
    float s = 0.f;
    for (int c = 0; c < 192; ++c) s += b_proj[c];
    wbar[192] = s * (1.f / 192.f);
  }
}

// ---------------------------------------------------------------------------
// main fused kernel: 512 blocks (bb = blk%8 -> XCD-stable image,
// wh = (blk>>3)&31, hseg = blk>>8 column half), 16 windows each.
// 512 threads = 8 waves; wave w owns head w.
// Barriers per iter: A (LN scratch), B (xn), B2 (af loaded, alias handoff),
// C (q/k/vw), D (logits).
// ---------------------------------------------------------------------------
__global__ __launch_bounds__(512, 2) void swin_kernel(
    const float* __restrict__ x,
    const float* __restrict__ gamma,
    const float* __restrict__ beta,
    const float* __restrict__ b_qkv,
    const __hip_bfloat16* __restrict__ wfrag,
    const float* __restrict__ wbar,
    float* __restrict__ out) {
  __shared__ __align__(16) char smem[LDS_BYTES];
  __hip_bfloat16* xn = (__hip_bfloat16*)(smem + OFF_Q);   // alias of lq (LN phase)
  __hip_bfloat16* lq = (__hip_bfloat16*)(smem + OFF_Q);
  __hip_bfloat16* lk = (__hip_bfloat16*)(smem + OFF_K);
  float* vwf = (float*)(smem + OFF_VW);
  float2* scratch = (float2*)(smem + OFF_K);              // alias of lk (LN phase)

  const int tid = threadIdx.x;
  const int w   = tid >> 6;
  const int l   = tid & 63;
  const int l15 = l & 15;
  const int lg  = l >> 4;
  const floatx4 fzero = {0.f, 0.f, 0.f, 0.f};

  const int p    = blockIdx.x;
  const int bb   = p & 7;              // image (== XCD under blockIdx%8 round-robin)
  const int wh   = (p >> 3) & 31;      // window row
  const int hseg = p >> 8;             // column half: ww = hseg*16 + it
  const int tr = l >> 3, tc = l & 7;   // lane <-> token (r,c) in 8x8 window
  const int c0 = w * 24;               // this wave's channel slice
  const float* xb = x + (size_t)bb * 192 * 65536 + (size_t)(wh * 8 + tr) * 256
                      + hseg * 128 + tc;

  float xr[24];
#pragma unroll
  for (int i = 0; i < 24; ++i) xr[i] = xb[(size_t)(c0 + i) * 65536];

#pragma unroll 1
  for (int it = 0; it < 16; ++it) {
    // ---------------- LayerNorm (lane = token, regs hold 24 channels) -------
    float s1 = 0.f, s2 = 0.f;
#pragma unroll
    for (int i = 0; i < 24; ++i) { s1 += xr[i]; s2 += xr[i] * xr[i]; }
    scratch[w * 64 + l] = make_float2(s1, s2);
    __syncthreads();                                           // (A)
    float ts = 0.f, tq = 0.f;
#pragma unroll
    for (int g = 0; g < 8; ++g) { float2 v = scratch[g * 64 + l]; ts += v.x; tq += v.y; }
    vwf[tid] = 0.f;   // reset vw accum for this window (fenced by A before / B after)
    const float mu   = ts * (1.f / 192.f);
    const float rstd = rsqrtf(tq * (1.f / 192.f) - mu * mu + LN_EPS);
    {
      short8 pk[3];
#pragma unroll
      for (int i = 0; i < 24; ++i) {
        float xv = (xr[i] - mu) * rstd * gamma[c0 + i] + beta[c0 + i];
        __hip_bfloat16 hb = __float2bfloat16(xv);
        short sv; __builtin_memcpy(&sv, &hb, 2);
        pk[i >> 3][i & 7] = sv;
      }
#pragma unroll
      for (int q2 = 0; q2 < 3; ++q2)          // b128 stores: conflict-free
        *(short8*)&xn[l * RXN + c0 + q2 * 8] = pk[q2];
    }
    __syncthreads();                                           // (B)

    // A fragments cached in regs (96 VGPRs) -- required: xn dies at B2
    short8 af[4][6];
#pragma unroll
    for (int mi = 0; mi < 4; ++mi)
#pragma unroll
      for (int ks = 0; ks < 6; ++ks)
        af[mi][ks] = *(const short8*)&xn[(16 * mi + l15) * RXN + 32 * ks + lg * 8];
    __syncthreads();                                           // (B2) xn dead; lq/lk writable

    // re-zero q/k head-pad columns (d=24..31) -- clobbered by the xn alias
    {
      const short8 zz = {0, 0, 0, 0, 0, 0, 0, 0};
#pragma unroll
      for (int i2 = tid; i2 < 1024; i2 += 512) {
        int sel = i2 & 1, r2 = i2 >> 1;                        // r2 = t*8 + head
        __hip_bfloat16* dst = (sel ? lk : lq) + (r2 >> 3) * RQK + (r2 & 7) * 32 + 24;
        *(short8*)dst = zz;                                    // 16B aligned (528t+64h+48)
      }
    }

    // ---------------- QKV GEMM: xn(64x192) @ w_qkv(192x576) -----------------
    for (int j = w; j < 36; j += 8) {          // n-tiles round-robin over waves
      floatx4 aa[4];
#pragma unroll
      for (int mi = 0; mi < 4; ++mi) aa[mi] = fzero;
      const short8* bp = (const short8*)wfrag + (size_t)(j * 384 + l);
#pragma unroll
      for (int ks = 0; ks < 6; ++ks) {
        short8 bf = bp[ks * 64];               // coalesced 1KB, L2-resident
#pragma unroll
        for (int mi = 0; mi < 4; ++mi) aa[mi] = mfma16(af[mi][ks], bf, aa[mi]);
      }
      const int n = 16 * j + l15;
      const float bias = b_qkv[n];
      if (j < 12) {                            // ---- Q (SCALE folded in) ----
        const int hh = n / 24, dd = n - hh * 24;
#pragma unroll
        for (int mi = 0; mi < 4; ++mi)
#pragma unroll
          for (int rg = 0; rg < 4; ++rg) {
            int t = 16 * mi + lg * 4 + rg;
            lq[t * RQK + hh * 32 + dd] = __float2bfloat16((aa[mi][rg] + bias) * SCALE_Q);
          }
      } else if (j < 24) {                     // ---- K ----
        const int cc = n - 192;
        const int hh = cc / 24, dd = cc - hh * 24;
#pragma unroll
        for (int mi = 0; mi < 4; ++mi)
#pragma unroll
          for (int rg = 0; rg < 4; ++rg) {
            int t = 16 * mi + lg * 4 + rg;
            lk[t * RQK + hh * 32 + dd] = __float2bfloat16(aa[mi][rg] + bias);
          }
      } else {                                 // ---- V: reduce straight to vw ----
        const int cc = n - 384;
        const int hh = cc / 24;                // head boundaries are 8-aligned (8|24)
        const float wbv = wbar[cc];
#pragma unroll
        for (int mi = 0; mi < 4; ++mi) {       // per-mi: small transient (part[4])
          float part[4];
#pragma unroll
          for (int rg = 0; rg < 4; ++rg)
            part[rg] = (aa[mi][rg] + bias) * wbv;
#pragma unroll
          for (int rg = 0; rg < 4; ++rg) {     // head-pure 8-lane reduction
            float t0 = part[rg];
            t0 += __shfl_xor(t0, 1);
            t0 += __shfl_xor(t0, 2);
            t0 += __shfl_xor(t0, 4);
            part[rg] = t0;
          }
          if ((l15 & 7) == 0)
#pragma unroll
            for (int rg = 0; rg < 4; ++rg) {
              int t = 16 * mi + lg * 4 + rg;
              atomicAdd(&vwf[hh * 64 + t], part[rg]);
            }
        }
      }
    }
    __syncthreads();                                           // (C)

    // ---------------- attention: wave w = head w -----------------------------
    {
      const int hh = w;
      short8 qf[4], kf[4];
#pragma unroll
      for (int i = 0; i < 4; ++i) {
        qf[i] = *(const short8*)&lq[(16 * i + l15) * RQK + hh * 32 + lg * 8];
        kf[i] = *(const short8*)&lk[(16 * i + l15) * RQK + hh * 32 + lg * 8];
      }
      float vwv[4];                            // this head's vw vector slice
#pragma unroll
      for (int j2 = 0; j2 < 4; ++j2) vwv[j2] = vwf[hh * 64 + 16 * j2 + l15];

      floatx4 sc[4][4];                        // S = q.k^T (scaled), then exp
#pragma unroll
      for (int i = 0; i < 4; ++i)
#pragma unroll
        for (int j2 = 0; j2 < 4; ++j2)
          sc[i][j2] = mfma16(qf[i], kf[j2], fzero);
#pragma unroll
      for (int i = 0; i < 4; ++i)
#pragma unroll
        for (int j2 = 0; j2 < 4; ++j2)
#pragma unroll
          for (int rg = 0; rg < 4; ++rg)
            sc[i][j2][rg] = exp2f(sc[i][j2][rg] * 1.44269504f);  // |s|<~40, fp32 safe

      // row-reduce in-register: D-layout row t = 16i + lg*4 + rg spans the 16
      // lanes of one lane-group (col = l15) x 4 j2 tiles.
      //   num[t] = sum_s P[t][s]*vw[s],  den[t] = sum_s P[t][s]
#pragma unroll
      for (int i = 0; i < 4; ++i) {
        float num[4] = {0.f, 0.f, 0.f, 0.f};
        float den[4] = {0.f, 0.f, 0.f, 0.f};
#pragma unroll
        for (int j2 = 0; j2 < 4; ++j2)
#pragma unroll
          for (int rg = 0; rg < 4; ++rg) {
            float pv = sc[i][j2][rg];
            den[rg] += pv;
            num[rg] = fmaf(pv, vwv[j2], num[rg]);
          }
#pragma unroll
        for (int m = 1; m < 16; m <<= 1)       // butterfly over l15 (in-group)
#pragma unroll
          for (int rg = 0; rg < 4; ++rg) {
            num[rg] += __shfl_xor(num[rg], m);
            den[rg] += __shfl_xor(den[rg], m);
          }
        // one unique lane per (i,rg) per lane-group stores the row's logit;
        // overwrites this wave's own (already-consumed) vw slice.
#pragma unroll
        for (int rg = 0; rg < 4; ++rg)
          if (l15 == i * 4 + rg)
            vwf[hh * 64 + 16 * i + lg * 4 + rg] = __fdividef(num[rg], den[rg]);
      }
    }
    __syncthreads();                                           // (D)

    // prefetch next window's x (live range overlaps only the epilogue; TLP
    // at 16 waves/CU covers the latency into next iteration's LN)
    if (it < 15) {
#pragma unroll
      for (int i = 0; i < 24; ++i)
        xr[i] = xb[(size_t)(c0 + i) * 65536 + (it + 1) * 8];
    }

    // ---------------- epilogue: sum 8 per-head logits -----------------------
    if (tid < 64) {
      float vL = wbar[192];
#pragma unroll
      for (int h8 = 0; h8 < 8; ++h8) vL += vwf[h8 * 64 + tid];
      out[(size_t)bb * 65536 + (size_t)(wh * 8 + (tid >> 3)) * 256
          + hseg * 128 + it * 8 + (tid & 7)] = 1.f / (1.f + __expf(-vL));
    }
  }
}

// ---------------------------------------------------------------------------
extern "C" void kernel_launch(void* const* d_in, const int* in_sizes, int n_in,
                              void* d_out, int out_size, void* d_ws, size_t ws_size,
                              hipStream_t stream) {
  const float* x      = (const float*)d_in[0];
  const float* gamma  = (const float*)d_in[1];
  const float* beta   = (const float*)d_in[2];
  const float* w_qkv  = (const float*)d_in[3];
  const float* b_qkv  = (const float*)d_in[4];
  const float* w_proj = (const float*)d_in[5];
  const float* b_proj = (const float*)d_in[6];
  float* out = (float*)d_out;

  __hip_bfloat16* wfrag = (__hip_bfloat16*)d_ws;          // 221184 B
  float* wbar = (float*)((char*)d_ws + 221184);           // 193 f32 (wbar + bbar)

  prep_kernel<<<54, 256, 0, stream>>>(w_qkv, w_proj, b_proj, wfrag, wbar);
  swin_kernel<<<512, 512, 0, stream>>>(x, gamma, beta, b_qkv, wfrag, wbar, out);
}